// Round 2
// baseline (403.068 us; speedup 1.0000x reference)
//
#include <hip/hip_runtime.h>

#define NM 23        // 3*K - 1, K = 8
#define ROWS 64

__device__ __forceinline__ float softplus_f(float v) {
  // stable: max(v,0) + log(1 + exp(-|v|))
  return fmaxf(v, 0.f) + __logf(1.f + __expf(-fabsf(v)));
}

// ---------------------------------------------------------------------------
// Fully fused: 64 rows/block, 1024 threads (16 waves), lane = row.
// MADE masks applied inline as scalar selects (all weight indices are
// wave-uniform via readfirstlane -> s_load + s_cselect, parallel to VALU).
// __launch_bounds__(1024, 8): force VGPR<=64 so 2 blocks (32 waves) fit/CU.
// ---------------------------------------------------------------------------
__global__ __launch_bounds__(1024, 8) void spline_kernel(
    const float* __restrict__ x,
    const float* __restrict__ W1, const float* __restrict__ b1,
    const float* __restrict__ W2, const float* __restrict__ b2,
    const float* __restrict__ W3, const float* __restrict__ b3,
    float* __restrict__ out, int B) {
  __shared__ float xs[ROWS][65];    // +1 pad: 2-way bank alias (free per m136)
  __shared__ float h1s[ROWS][65];   // reused as z-staging after layer 2
  __shared__ float h2s[ROWS][33];
  __shared__ float ldp[16][ROWS];

  const int t = threadIdx.x;
  const int b0 = blockIdx.x * ROWS;

  // ---- stage x tile: exactly one float4 per thread (coalesced) ----
  {
    const int rr = t >> 4;
    const int c4 = (t & 15) * 4;
    const float4 v =
        *reinterpret_cast<const float4*>(x + (size_t)b0 * 64 + (size_t)t * 4);
    xs[rr][c4 + 0] = v.x; xs[rr][c4 + 1] = v.y;
    xs[rr][c4 + 2] = v.z; xs[rr][c4 + 3] = v.w;
  }
  __syncthreads();

  const int r  = t & 63;                                   // lane = row
  const int wv = __builtin_amdgcn_readfirstlane(t >> 6);   // wave id 0..15

  // ---- layer 1: h1[r][i], i in [wv*4, wv*4+4) ----
  // mask m1[i][d] = (d < (i%63)+1)
  {
    float acc1[4];
    #pragma unroll
    for (int ii = 0; ii < 4; ++ii) acc1[ii] = b1[wv * 4 + ii];
    #pragma unroll 4
    for (int dd = 0; dd < 64; ++dd) {
      const float xv = xs[r][dd];
      #pragma unroll
      for (int ii = 0; ii < 4; ++ii) {
        const int i = wv * 4 + ii;
        const int deg = (i % 63) + 1;                      // uniform
        const float w = (dd < deg) ? W1[i * 64 + dd] : 0.f; // scalar select
        acc1[ii] = fmaf(xv, w, acc1[ii]);
      }
    }
    #pragma unroll
    for (int ii = 0; ii < 4; ++ii) h1s[r][wv * 4 + ii] = fmaxf(acc1[ii], 0.f);
  }
  __syncthreads();

  // ---- layer 2: h2[r][j], j in [wv*2, wv*2+2) ----
  // mask m2[j][i] = ((i%63) <= j)  i.e.  (i <= j) || (i == 63)
  {
    float acc2[2];
    #pragma unroll
    for (int jj = 0; jj < 2; ++jj) acc2[jj] = b2[wv * 2 + jj];
    #pragma unroll 4
    for (int i2 = 0; i2 < 64; ++i2) {
      const float hv = h1s[r][i2];
      #pragma unroll
      for (int jj = 0; jj < 2; ++jj) {
        const int j = wv * 2 + jj;
        const bool on = (i2 <= j) || (i2 == 63);           // uniform
        const float w = on ? W2[j * 64 + i2] : 0.f;        // scalar select
        acc2[jj] = fmaf(hv, w, acc2[jj]);
      }
    }
    #pragma unroll
    for (int jj = 0; jj < 2; ++jj) h2s[r][wv * 2 + jj] = fmaxf(acc2[jj], 0.f);
  }
  __syncthreads();

  // ---- h2 row into registers ----
  float h2r[32];
  #pragma unroll
  for (int k = 0; k < 32; ++k) h2r[k] = h2s[r][k];

  float ldacc = 0.f;

  // ---- layer 3 + spline: 4 d-values per thread ----
  // mask m3[(m,d)][k] = (k < d)
  #pragma unroll 1
  for (int di = 0; di < 4; ++di) {
    const int dU = __builtin_amdgcn_readfirstlane(wv * 4 + di);

    float p[NM];
    #pragma unroll
    for (int m = 0; m < NM; ++m) {
      float acc = b3[m * 64 + dU];
      const float* wrow = W3 + (size_t)(m * 64 + dU) * 32;
      #pragma unroll
      for (int kk = 0; kk < 32; ++kk) {
        const float w = (kk < dU) ? wrow[kk] : 0.f;        // scalar select
        acc = fmaf(h2r[kk], w, acc);
      }
      p[m] = acc;
    }

    const float xv = xs[r][dU];
    const float xc = fminf(fmaxf(xv, -3.f), 3.f);

    // softmax over widths logits p[0..7]
    float mw = p[0];
    #pragma unroll
    for (int k = 1; k < 8; ++k) mw = fmaxf(mw, p[k]);
    float ew[8], sw = 0.f;
    #pragma unroll
    for (int k = 0; k < 8; ++k) { ew[k] = __expf(p[k] - mw); sw += ew[k]; }
    const float invw = 1.f / sw;

    // softmax over heights logits p[8..15]
    float mh = p[8];
    #pragma unroll
    for (int k = 1; k < 8; ++k) mh = fmaxf(mh, p[8 + k]);
    float eh[8], sh = 0.f;
    #pragma unroll
    for (int k = 0; k < 8; ++k) { eh[k] = __expf(p[8 + k] - mh); sh += eh[k]; }
    const float invh = 1.f / sh;

    const float WSC = 1.0f - 1e-3f * 8.0f;   // 1 - MIN_BIN_WIDTH*K
    float cumw[9], cumh[9];
    cumw[0] = -3.f; cumh[0] = -3.f;
    float cw = 0.f, ch = 0.f;
    #pragma unroll
    for (int k = 0; k < 7; ++k) {
      cw += 1e-3f + WSC * (ew[k] * invw);
      ch += 1e-3f + WSC * (eh[k] * invh);
      cumw[k + 1] = fmaf(6.f, cw, -3.f);
      cumh[k + 1] = fmaf(6.f, ch, -3.f);
    }
    cumw[8] = 3.f; cumh[8] = 3.f;

    float derivs[9];
    derivs[0] = 1.f; derivs[8] = 1.f;
    #pragma unroll
    for (int k = 0; k < 7; ++k) derivs[k + 1] = 1e-3f + softplus_f(p[16 + k]);

    // bin select: idx = sum(xc >= cumw[k]+EPS) - 1, clipped to [0,7]
    float xk = cumw[0], xk1 = cumw[1];
    float yk = cumh[0], yk1 = cumh[1];
    float dk = derivs[0], dk1 = derivs[1];
    #pragma unroll
    for (int k = 1; k < 8; ++k) {
      const bool s = xc >= cumw[k] + 1e-6f;
      xk  = s ? cumw[k]       : xk;
      xk1 = s ? cumw[k + 1]   : xk1;
      yk  = s ? cumh[k]       : yk;
      yk1 = s ? cumh[k + 1]   : yk1;
      dk  = s ? derivs[k]     : dk;
      dk1 = s ? derivs[k + 1] : dk1;
    }

    const float wk = xk1 - xk, hk = yk1 - yk;
    const float invwk = 1.f / wk;
    const float delta = hk * invwk;
    const float theta = (xc - xk) * invwk;
    const float omt = 1.f - theta;
    const float tt = theta * omt;
    const float th2 = theta * theta;
    const float num = hk * (delta * th2 + dk * tt);
    const float den = delta + (dk + dk1 - 2.f * delta) * tt;
    const float yv = yk + num / den;
    const float dnum = delta * delta * (dk1 * th2 + 2.f * delta * tt + dk * omt * omt);
    const float ldv = __logf(dnum) - 2.f * __logf(den);

    const bool inside = (xv >= -3.f) && (xv <= 3.f);
    h1s[r][dU] = inside ? yv : xv;           // z staging (h1s free after layer2)
    ldacc += inside ? ldv : 0.f;
  }

  ldp[wv][r] = ldacc;
  __syncthreads();

  // ---- coalesced z write: one float4 per thread ----
  {
    const int rr = t >> 4;
    const int c4 = (t & 15) * 4;
    const float4 v = make_float4(h1s[rr][c4 + 0], h1s[rr][c4 + 1],
                                 h1s[rr][c4 + 2], h1s[rr][c4 + 3]);
    *reinterpret_cast<float4*>(out + (size_t)b0 * 64 + (size_t)t * 4) = v;
  }
  // ---- log-det sum output ----
  if (t < 64) {
    float s = 0.f;
    #pragma unroll
    for (int w = 0; w < 16; ++w) s += ldp[w][t];
    out[(size_t)B * 64 + b0 + t] = s;
  }
}

extern "C" void kernel_launch(void* const* d_in, const int* in_sizes, int n_in,
                              void* d_out, int out_size, void* d_ws, size_t ws_size,
                              hipStream_t stream) {
  const float* x  = (const float*)d_in[0];
  const float* W1 = (const float*)d_in[1];
  const float* b1 = (const float*)d_in[2];
  const float* W2 = (const float*)d_in[3];
  const float* b2 = (const float*)d_in[4];
  const float* W3 = (const float*)d_in[5];
  const float* b3 = (const float*)d_in[6];
  float* out = (float*)d_out;

  const int B = in_sizes[0] / 64;     // 32768

  spline_kernel<<<B / ROWS, 1024, 0, stream>>>(
      x, W1, b1, W2, b2, W3, b3, out, B);
}